// Round 1
// baseline (3676.155 us; speedup 1.0000x reference)
//
#include <hip/hip_runtime.h>
#include <cstdint>

// Transformer encoder layer, fp32, correctness-first baseline.
// B=4 S=2048 D=1024 H=16 depth=64 DFF=4096.
// Workspace layout (floats): q[8M] k[8M] v[8M] ctx[8M] hbuf[16M] = 48M floats = 192 MB.
// Reuse: attn_out:=q, out1:=v, ffn:=k (all dead by then; stream-ordered).

#define BATCH 4
#define SEQ   2048
#define DM    1024
#define NH    16
#define DEPTH 64
#define DFF_  4096
#define EPSF  1e-6f

// ---------------- GEMM: C = act(A @ W + bias) ----------------
// A:[M,K] row-major, W:[K,N] row-major, bias:[N].
// SPLIT=1 -> write C in [B,H,S,DEPTH] split-head layout (requires N==DM, M==B*SEQ).
// 128x128 tile, BK=16, 256 threads, 8x8 micro-tile (split 4+4 at +64 for LDS bank spread).
template<int ACT, int SPLIT>
__global__ __launch_bounds__(256)
void gemm_kernel(const float* __restrict__ A, const float* __restrict__ W,
                 const float* __restrict__ bias, float* __restrict__ C,
                 int M, int N, int K)
{
  constexpr int BM = 128, BN = 128, BK = 16;
  __shared__ float As[BK][BM + 4];   // transposed: As[k][m]; +4 pad -> 2-way max on staging writes
  __shared__ float Ws[BK][BN];       // natural:    Ws[k][n]
  const int tid = threadIdx.x;
  const int tr = tid >> 4;           // 0..15 (row group)
  const int tc = tid & 15;           // 0..15 (col group)
  const int m0 = blockIdx.y * BM;
  const int n0 = blockIdx.x * BN;

  float acc[8][8];
#pragma unroll
  for (int i = 0; i < 8; ++i)
#pragma unroll
    for (int j = 0; j < 8; ++j) acc[i][j] = 0.f;

  for (int k0 = 0; k0 < K; k0 += BK) {
    // stage A tile (transposed into LDS): 512 float4, 2 per thread
#pragma unroll
    for (int ph = 0; ph < 2; ++ph) {
      int a = tid + ph * 256;
      int m = a >> 2;                // 0..127
      int k4 = a & 3;                // 0..3 (which float4 of the row's 16 k's)
      float4 va = *(const float4*)(A + (size_t)(m0 + m) * K + k0 + k4 * 4);
      As[k4 * 4 + 0][m] = va.x;
      As[k4 * 4 + 1][m] = va.y;
      As[k4 * 4 + 2][m] = va.z;
      As[k4 * 4 + 3][m] = va.w;
    }
    // stage W tile (natural): 512 float4, 2 per thread
#pragma unroll
    for (int ph = 0; ph < 2; ++ph) {
      int a = tid + ph * 256;
      int kk = a >> 5;               // 0..15
      int n4 = a & 31;               // 0..31
      *(float4*)&Ws[kk][n4 * 4] =
          *(const float4*)(W + (size_t)(k0 + kk) * N + n0 + n4 * 4);
    }
    __syncthreads();
#pragma unroll
    for (int k = 0; k < BK; ++k) {
      float a0[4], a1[4], b0[4], b1[4];
      *(float4*)a0 = *(const float4*)&As[k][tr * 4];
      *(float4*)a1 = *(const float4*)&As[k][tr * 4 + 64];
      *(float4*)b0 = *(const float4*)&Ws[k][tc * 4];
      *(float4*)b1 = *(const float4*)&Ws[k][tc * 4 + 64];
#pragma unroll
      for (int i = 0; i < 4; ++i)
#pragma unroll
        for (int j = 0; j < 4; ++j) {
          acc[i][j]         += a0[i] * b0[j];
          acc[i][j + 4]     += a0[i] * b1[j];
          acc[i + 4][j]     += a1[i] * b0[j];
          acc[i + 4][j + 4] += a1[i] * b1[j];
        }
    }
    __syncthreads();
  }

  // epilogue: bias (+relu) (+split-head scatter)
#pragma unroll
  for (int ih = 0; ih < 2; ++ih)
#pragma unroll
    for (int i = 0; i < 4; ++i) {
      int row = m0 + ih * 64 + tr * 4 + i;
#pragma unroll
      for (int jh = 0; jh < 2; ++jh) {
        int col = n0 + jh * 64 + tc * 4;
        float4 r;
        r.x = acc[ih * 4 + i][jh * 4 + 0] + bias[col + 0];
        r.y = acc[ih * 4 + i][jh * 4 + 1] + bias[col + 1];
        r.z = acc[ih * 4 + i][jh * 4 + 2] + bias[col + 2];
        r.w = acc[ih * 4 + i][jh * 4 + 3] + bias[col + 3];
        if (ACT) {
          r.x = fmaxf(r.x, 0.f); r.y = fmaxf(r.y, 0.f);
          r.z = fmaxf(r.z, 0.f); r.w = fmaxf(r.w, 0.f);
        }
        if (SPLIT) {
          int b  = row >> 11;            // SEQ = 2048
          int s  = row & (SEQ - 1);
          int hh = col >> 6;             // DEPTH = 64
          int d  = col & 63;
          *(float4*)(C + (((size_t)(b * NH + hh) * SEQ + s) * DEPTH + d)) = r;
        } else {
          *(float4*)(C + (size_t)row * N + col) = r;
        }
      }
    }
}

// ---------------- Flash-style attention, fp32 ----------------
// grid: (SEQ/64, B*H); block 256. Q,K,V in [B,H,S,64]; ctx out in [B,S,D].
__global__ __launch_bounds__(256)
void attn_kernel(const float* __restrict__ Qm, const float* __restrict__ Km,
                 const float* __restrict__ Vm, const float* __restrict__ mask,
                 float* __restrict__ ctx)
{
  __shared__ float Qt[DEPTH][68];   // [d][q-row]
  __shared__ float Kt[DEPTH][68];   // [d][k-row]
  __shared__ float Vs[64][68];      // [k-row][d]
  __shared__ float Ps[64][68];      // [q-row][k-col]
  const int tid = threadIdx.x;
  const int tr = tid >> 4, tc = tid & 15;
  const int bh = blockIdx.y;
  const int b = bh >> 4, hh = bh & 15;
  const int q0 = blockIdx.x * 64;
  const size_t base = (size_t)bh * SEQ * DEPTH;

  // load Q tile transposed (once)
#pragma unroll
  for (int ph = 0; ph < 4; ++ph) {
    int a = tid + ph * 256;
    int r = a >> 4, d4 = a & 15;
    float4 v = *(const float4*)(Qm + base + (size_t)(q0 + r) * DEPTH + d4 * 4);
    Qt[d4 * 4 + 0][r] = v.x; Qt[d4 * 4 + 1][r] = v.y;
    Qt[d4 * 4 + 2][r] = v.z; Qt[d4 * 4 + 3][r] = v.w;
  }

  float m_i[4], l_i[4], o[4][4];
#pragma unroll
  for (int i = 0; i < 4; ++i) {
    m_i[i] = -1e30f; l_i[i] = 0.f;
#pragma unroll
    for (int j = 0; j < 4; ++j) o[i][j] = 0.f;
  }

  for (int kv0 = 0; kv0 < SEQ; kv0 += 64) {
    __syncthreads();   // previous tile's readers of Kt/Vs done (also covers Qt on iter 0)
#pragma unroll
    for (int ph = 0; ph < 4; ++ph) {
      int a = tid + ph * 256;
      int r = a >> 4, d4 = a & 15;
      float4 kv = *(const float4*)(Km + base + (size_t)(kv0 + r) * DEPTH + d4 * 4);
      Kt[d4 * 4 + 0][r] = kv.x; Kt[d4 * 4 + 1][r] = kv.y;
      Kt[d4 * 4 + 2][r] = kv.z; Kt[d4 * 4 + 3][r] = kv.w;
      *(float4*)&Vs[r][d4 * 4] =
          *(const float4*)(Vm + base + (size_t)(kv0 + r) * DEPTH + d4 * 4);
    }
    __syncthreads();

    // scores: s[i][j] = sum_d Q[q0+tr*4+i][d] * K[kv0+tc*4+j][d]
    float s[4][4];
#pragma unroll
    for (int i = 0; i < 4; ++i)
#pragma unroll
      for (int j = 0; j < 4; ++j) s[i][j] = 0.f;
    for (int d = 0; d < DEPTH; ++d) {
      float qv[4], kv[4];
      *(float4*)qv = *(const float4*)&Qt[d][tr * 4];
      *(float4*)kv = *(const float4*)&Kt[d][tc * 4];
#pragma unroll
      for (int i = 0; i < 4; ++i)
#pragma unroll
        for (int j = 0; j < 4; ++j) s[i][j] += qv[i] * kv[j];
    }
    float mk[4];
#pragma unroll
    for (int j = 0; j < 4; ++j)
      mk[j] = mask[(size_t)b * SEQ + kv0 + tc * 4 + j] * -1e9f;

    // online softmax per row (row stats replicated across the 16 tc lanes)
#pragma unroll
    for (int i = 0; i < 4; ++i) {
      float p[4];
#pragma unroll
      for (int j = 0; j < 4; ++j) s[i][j] = s[i][j] * 0.125f + mk[j];
      float mt = fmaxf(fmaxf(s[i][0], s[i][1]), fmaxf(s[i][2], s[i][3]));
#pragma unroll
      for (int mm = 1; mm < 16; mm <<= 1) mt = fmaxf(mt, __shfl_xor(mt, mm));
      float mnew = fmaxf(m_i[i], mt);
      float sc = __expf(m_i[i] - mnew);
      float rs = 0.f;
#pragma unroll
      for (int j = 0; j < 4; ++j) { p[j] = __expf(s[i][j] - mnew); rs += p[j]; }
#pragma unroll
      for (int mm = 1; mm < 16; mm <<= 1) rs += __shfl_xor(rs, mm);
      l_i[i] = l_i[i] * sc + rs;
      m_i[i] = mnew;
#pragma unroll
      for (int j = 0; j < 4; ++j) o[i][j] *= sc;
      *(float4*)&Ps[tr * 4 + i][tc * 4] = *(float4*)p;
    }
    __syncthreads();

    // o += P @ V
#pragma unroll 4
    for (int j = 0; j < 64; ++j) {
      float vv[4];
      *(float4*)vv = *(const float4*)&Vs[j][tc * 4];
      float pj[4];
#pragma unroll
      for (int i = 0; i < 4; ++i) pj[i] = Ps[tr * 4 + i][j];
#pragma unroll
      for (int i = 0; i < 4; ++i)
#pragma unroll
        for (int dj = 0; dj < 4; ++dj) o[i][dj] += pj[i] * vv[dj];
    }
  }

  // normalize + write ctx in [B,S,D]
#pragma unroll
  for (int i = 0; i < 4; ++i) {
    float inv = 1.f / l_i[i];
    float4 r;
    r.x = o[i][0] * inv; r.y = o[i][1] * inv;
    r.z = o[i][2] * inv; r.w = o[i][3] * inv;
    *(float4*)(ctx + (size_t)(b * SEQ + q0 + tr * 4 + i) * DM + hh * 64 + tc * 4) = r;
  }
}

// ---------------- out = LayerNorm(X + Y) * g + beta ----------------
// one block (256 thr) per row of 1024
__global__ __launch_bounds__(256)
void add_ln_kernel(const float* __restrict__ X, const float* __restrict__ Y,
                   const float* __restrict__ g, const float* __restrict__ be,
                   float* __restrict__ out)
{
  __shared__ float red[8];
  const int row = blockIdx.x;
  const int tid = threadIdx.x;
  const size_t off = (size_t)row * DM + tid * 4;
  float4 xv = *(const float4*)(X + off);
  float4 yv = *(const float4*)(Y + off);
  float v0 = xv.x + yv.x, v1 = xv.y + yv.y, v2 = xv.z + yv.z, v3 = xv.w + yv.w;
  float s = v0 + v1 + v2 + v3;
#pragma unroll
  for (int m = 1; m < 64; m <<= 1) s += __shfl_xor(s, m);
  if ((tid & 63) == 0) red[tid >> 6] = s;
  __syncthreads();
  float mean = (red[0] + red[1] + red[2] + red[3]) * (1.f / DM);
  float d0 = v0 - mean, d1 = v1 - mean, d2 = v2 - mean, d3 = v3 - mean;
  float sq = d0 * d0 + d1 * d1 + d2 * d2 + d3 * d3;
#pragma unroll
  for (int m = 1; m < 64; m <<= 1) sq += __shfl_xor(sq, m);
  if ((tid & 63) == 0) red[4 + (tid >> 6)] = sq;
  __syncthreads();
  float var = (red[4] + red[5] + red[6] + red[7]) * (1.f / DM);
  float inv = rsqrtf(var + EPSF);
  int col = tid * 4;
  float4 r;
  r.x = d0 * inv * g[col + 0] + be[col + 0];
  r.y = d1 * inv * g[col + 1] + be[col + 1];
  r.z = d2 * inv * g[col + 2] + be[col + 2];
  r.w = d3 * inv * g[col + 3] + be[col + 3];
  *(float4*)(out + off) = r;
}

extern "C" void kernel_launch(void* const* d_in, const int* in_sizes, int n_in,
                              void* d_out, int out_size, void* d_ws, size_t ws_size,
                              hipStream_t stream)
{
  const float* x    = (const float*)d_in[0];
  const float* mask = (const float*)d_in[1];
  const float* wq   = (const float*)d_in[2];
  const float* bq   = (const float*)d_in[3];
  const float* wk   = (const float*)d_in[4];
  const float* bk   = (const float*)d_in[5];
  const float* wv   = (const float*)d_in[6];
  const float* bv   = (const float*)d_in[7];
  const float* wo   = (const float*)d_in[8];
  const float* bo   = (const float*)d_in[9];
  const float* w1   = (const float*)d_in[10];
  const float* b1   = (const float*)d_in[11];
  const float* w2   = (const float*)d_in[12];
  const float* b2   = (const float*)d_in[13];
  const float* g1   = (const float*)d_in[14];
  const float* be1  = (const float*)d_in[15];
  const float* g2   = (const float*)d_in[16];
  const float* be2  = (const float*)d_in[17];
  float* out = (float*)d_out;
  float* ws  = (float*)d_ws;

  const size_t MSD = (size_t)BATCH * SEQ * DM;   // 8M floats
  float* q    = ws;
  float* k    = ws + MSD;
  float* v    = ws + 2 * MSD;
  float* ctx  = ws + 3 * MSD;
  float* hbuf = ws + 4 * MSD;                    // 16M floats (4096 x 4096)
  float* attn_out = q;   // q dead after attention
  float* out1     = v;   // v dead after attention
  float* ffn      = k;   // k dead after attention

  const int M = BATCH * SEQ;   // 8192
  dim3 blk(256);

  gemm_kernel<0, 1><<<dim3(DM / 128, M / 128), blk, 0, stream>>>(x, wq, bq, q, M, DM, DM);
  gemm_kernel<0, 1><<<dim3(DM / 128, M / 128), blk, 0, stream>>>(x, wk, bk, k, M, DM, DM);
  gemm_kernel<0, 1><<<dim3(DM / 128, M / 128), blk, 0, stream>>>(x, wv, bv, v, M, DM, DM);

  attn_kernel<<<dim3(SEQ / 64, BATCH * NH), blk, 0, stream>>>(q, k, v, mask, ctx);

  gemm_kernel<0, 0><<<dim3(DM / 128, M / 128), blk, 0, stream>>>(ctx, wo, bo, attn_out, M, DM, DM);
  add_ln_kernel<<<dim3(M), blk, 0, stream>>>(x, attn_out, g1, be1, out1);

  // FFN in 2 chunks of 4096 rows (keeps hidden buffer at 64 MB; full CU fill per launch)
  for (int c = 0; c < 2; ++c) {
    const float* a1p = out1 + (size_t)c * 4096 * DM;
    gemm_kernel<1, 0><<<dim3(DFF_ / 128, 4096 / 128), blk, 0, stream>>>(
        a1p, w1, b1, hbuf, 4096, DFF_, DM);
    gemm_kernel<0, 0><<<dim3(DM / 128, 4096 / 128), blk, 0, stream>>>(
        hbuf, w2, b2, ffn + (size_t)c * 4096 * DM, 4096, DM, DFF_);
  }
  add_ln_kernel<<<dim3(M), blk, 0, stream>>>(out1, ffn, g2, be2, out);
}

// Round 3
// 1669.063 us; speedup vs baseline: 2.2025x; 2.2025x over previous
//
#include <hip/hip_runtime.h>
#include <cstdint>

// Transformer encoder layer. bf16-MFMA GEMMs + fp32 flash attention.
// B=4 S=2048 D=1024 H=16 depth=64 DFF=4096.
//
// Workspace layout (byte offsets, total 152 MB):
//   [0,32M)    q fp32 split-head   -> attn_out fp32 -> ffn fp32
//   [32,64M)   k fp32 split-head   -> out1 fp32
//   [64,96M)   v fp32 split-head   -> hbuf bf16 (FFN hidden, per 4096-row chunk)
//   [96,112M)  ctx bf16 [B,S,D]    -> out1b bf16
//   [112,128M) xb bf16
//   [128,136M) wqt,wkt,wvt,wot bf16 [N,K]
//   [136,152M) w1t (8M), w2t (8M) bf16 [N,K]

#define BATCH 4
#define SEQ   2048
#define DM    1024
#define NH    16
#define DEPTH 64
#define DFF_  4096
#define EPSF  1e-6f

typedef short bf16x8 __attribute__((ext_vector_type(8)));
typedef float f32x4  __attribute__((ext_vector_type(4)));

__device__ __forceinline__ unsigned short f2bf(float f) {
  union { float f; unsigned int u; } v; v.f = f;
  unsigned int u = v.u;
  return (unsigned short)((u + 0x7fffu + ((u >> 16) & 1u)) >> 16);  // RNE
}

__device__ __forceinline__ void gload_lds16(const void* g, void* l) {
  __builtin_amdgcn_global_load_lds(
      (const __attribute__((address_space(1))) unsigned int*)g,
      (__attribute__((address_space(3))) unsigned int*)l, 16, 0, 0);
}

// ---------------- bf16 MFMA GEMM: C = act(A @ Bt^T + bias) ----------------
// A:[M,K] bf16 row-major. Bt:[N,K] bf16 row-major (pre-transposed weight).
// 128x128 tile, BK=32, 4 waves (2x2), each wave 64x64 = 4x4 frags of 16x16x32.
// LDS rows are 64 B (32 bf16); 16B-chunk c of row r holds global chunk c^(r&3)
// (inverse-swizzled global source, linear global_load_lds dest, swizzled read).
template<int ACT, int SPLIT, int OUT_BF16>
__global__ __launch_bounds__(256)
void gemm_mfma(const unsigned short* __restrict__ A, const unsigned short* __restrict__ Bt,
               const float* __restrict__ bias, float* __restrict__ Cf,
               unsigned short* __restrict__ Cb, int M, int N, int K)
{
  __shared__ unsigned short As[128 * 32];
  __shared__ unsigned short Bs[128 * 32];
  const int tid  = threadIdx.x;
  const int wid  = tid >> 6;
  const int lane = tid & 63;
  const int wr = wid >> 1, wc = wid & 1;
  const int m0 = blockIdx.y * 128;
  const int n0 = blockIdx.x * 128;

  const int lrow   = lane >> 2;                    // staging: row within 16-row seg
  const int lchunk = (lane & 3) ^ (lrow & 3);      // inverse-swizzled source chunk
  const int fr = lane & 15;                        // fragment row/col
  const int kh = lane >> 4;                        // k-quarter (8 bf16 each)

  f32x4 acc[4][4] = {};

  const char* gA = (const char*)A;
  const char* gB = (const char*)Bt;
  char* lA = (char*)As;
  char* lB = (char*)Bs;

  for (int k0 = 0; k0 < K; k0 += 32) {
#pragma unroll
    for (int seg = 0; seg < 2; ++seg) {
      int r = wid * 32 + seg * 16 + lrow;          // tile row staged by this lane
      gload_lds16(gA + ((size_t)(m0 + r) * K + k0) * 2 + lchunk * 16,
                  lA + (wid * 32 + seg * 16) * 64);
      gload_lds16(gB + ((size_t)(n0 + r) * K + k0) * 2 + lchunk * 16,
                  lB + (wid * 32 + seg * 16) * 64);
    }
    __syncthreads();   // compiler drains vmcnt before s_barrier
    bf16x8 af[4], bg[4];
#pragma unroll
    for (int i = 0; i < 4; ++i) {
      af[i] = *(const bf16x8*)(lA + (wr * 64 + i * 16 + fr) * 64 + ((kh ^ (fr & 3)) * 16));
      bg[i] = *(const bf16x8*)(lB + (wc * 64 + i * 16 + fr) * 64 + ((kh ^ (fr & 3)) * 16));
    }
#pragma unroll
    for (int i = 0; i < 4; ++i)
#pragma unroll
      for (int j = 0; j < 4; ++j)
        acc[i][j] = __builtin_amdgcn_mfma_f32_16x16x32_bf16(af[i], bg[j], acc[i][j], 0, 0, 0);
    __syncthreads();
  }

  // epilogue: C/D layout col=lane&15, row=(lane>>4)*4+reg  [m89/m91]
  const int rbase = (lane >> 4) * 4;
  const int ccol  = lane & 15;
  float bcol[4];
#pragma unroll
  for (int j = 0; j < 4; ++j) bcol[j] = bias[n0 + wc * 64 + j * 16 + ccol];
#pragma unroll
  for (int i = 0; i < 4; ++i)
#pragma unroll
    for (int jj = 0; jj < 4; ++jj) {
      int row = m0 + wr * 64 + i * 16 + rbase + jj;
#pragma unroll
      for (int j = 0; j < 4; ++j) {
        float vv = acc[i][j][jj] + bcol[j];
        if (ACT) vv = fmaxf(vv, 0.f);
        int col = n0 + wc * 64 + j * 16 + ccol;
        if (SPLIT) {   // write fp32 [B,H,S,DEPTH]
          int b = row >> 11, s = row & (SEQ - 1);
          int hh = col >> 6, d = col & 63;
          Cf[(((size_t)(b * NH + hh)) * SEQ + s) * DEPTH + d] = vv;
        } else if (OUT_BF16) {
          Cb[(size_t)row * N + col] = f2bf(vv);
        } else {
          Cf[(size_t)row * N + col] = vv;
        }
      }
    }
}

// ---------------- weight fp32 [K,N] -> bf16 [N,K] transpose ----------------
__global__ __launch_bounds__(256)
void transpose_to_bf16(const float* __restrict__ W, unsigned short* __restrict__ Wt,
                       int K, int N)
{
  __shared__ float t[32][33];
  const int tx = threadIdx.x & 31;
  const int ty = threadIdx.x >> 5;      // 0..7
  const int n0 = blockIdx.x * 32;
  const int k0 = blockIdx.y * 32;
#pragma unroll
  for (int i = 0; i < 4; ++i) {
    int r = ty + i * 8;
    t[r][tx] = W[(size_t)(k0 + r) * N + n0 + tx];
  }
  __syncthreads();
#pragma unroll
  for (int i = 0; i < 4; ++i) {
    int r = ty + i * 8;
    Wt[(size_t)(n0 + r) * K + k0 + tx] = f2bf(t[tx][r]);
  }
}

// ---------------- fp32 -> bf16 elementwise ----------------
__global__ __launch_bounds__(256)
void convert_bf16(const float* __restrict__ X, unsigned short* __restrict__ Xb, int n4)
{
  int i = blockIdx.x * 256 + threadIdx.x;
  if (i < n4) {
    float4 v = ((const float4*)X)[i];
    ushort4 r;
    r.x = f2bf(v.x); r.y = f2bf(v.y); r.z = f2bf(v.z); r.w = f2bf(v.w);
    ((ushort4*)Xb)[i] = r;
  }
}

// ---------------- Flash-style attention, fp32 compute, bf16 ctx out ----------------
__global__ __launch_bounds__(256)
void attn_kernel(const float* __restrict__ Qm, const float* __restrict__ Km,
                 const float* __restrict__ Vm, const float* __restrict__ mask,
                 unsigned short* __restrict__ ctxb)
{
  __shared__ float Qt[DEPTH][68];
  __shared__ float Kt[DEPTH][68];
  __shared__ float Vs[64][68];
  __shared__ float Ps[64][68];
  const int tid = threadIdx.x;
  const int tr = tid >> 4, tc = tid & 15;
  const int bh = blockIdx.y;
  const int b = bh >> 4, hh = bh & 15;
  const int q0 = blockIdx.x * 64;
  const size_t base = (size_t)bh * SEQ * DEPTH;

#pragma unroll
  for (int ph = 0; ph < 4; ++ph) {
    int a = tid + ph * 256;
    int r = a >> 4, d4 = a & 15;
    float4 v = *(const float4*)(Qm + base + (size_t)(q0 + r) * DEPTH + d4 * 4);
    Qt[d4 * 4 + 0][r] = v.x; Qt[d4 * 4 + 1][r] = v.y;
    Qt[d4 * 4 + 2][r] = v.z; Qt[d4 * 4 + 3][r] = v.w;
  }

  float m_i[4], l_i[4], o[4][4];
#pragma unroll
  for (int i = 0; i < 4; ++i) {
    m_i[i] = -1e30f; l_i[i] = 0.f;
#pragma unroll
    for (int j = 0; j < 4; ++j) o[i][j] = 0.f;
  }

  for (int kv0 = 0; kv0 < SEQ; kv0 += 64) {
    __syncthreads();
#pragma unroll
    for (int ph = 0; ph < 4; ++ph) {
      int a = tid + ph * 256;
      int r = a >> 4, d4 = a & 15;
      float4 kv = *(const float4*)(Km + base + (size_t)(kv0 + r) * DEPTH + d4 * 4);
      Kt[d4 * 4 + 0][r] = kv.x; Kt[d4 * 4 + 1][r] = kv.y;
      Kt[d4 * 4 + 2][r] = kv.z; Kt[d4 * 4 + 3][r] = kv.w;
      *(float4*)&Vs[r][d4 * 4] =
          *(const float4*)(Vm + base + (size_t)(kv0 + r) * DEPTH + d4 * 4);
    }
    __syncthreads();

    float s[4][4];
#pragma unroll
    for (int i = 0; i < 4; ++i)
#pragma unroll
      for (int j = 0; j < 4; ++j) s[i][j] = 0.f;
    for (int d = 0; d < DEPTH; ++d) {
      float qv[4], kv[4];
      *(float4*)qv = *(const float4*)&Qt[d][tr * 4];
      *(float4*)kv = *(const float4*)&Kt[d][tc * 4];
#pragma unroll
      for (int i = 0; i < 4; ++i)
#pragma unroll
        for (int j = 0; j < 4; ++j) s[i][j] += qv[i] * kv[j];
    }
    float mk[4];
#pragma unroll
    for (int j = 0; j < 4; ++j)
      mk[j] = mask[(size_t)b * SEQ + kv0 + tc * 4 + j] * -1e9f;

#pragma unroll
    for (int i = 0; i < 4; ++i) {
      float p[4];
#pragma unroll
      for (int j = 0; j < 4; ++j) s[i][j] = s[i][j] * 0.125f + mk[j];
      float mt = fmaxf(fmaxf(s[i][0], s[i][1]), fmaxf(s[i][2], s[i][3]));
#pragma unroll
      for (int mm = 1; mm < 16; mm <<= 1) mt = fmaxf(mt, __shfl_xor(mt, mm));
      float mnew = fmaxf(m_i[i], mt);
      float sc = __expf(m_i[i] - mnew);
      float rs = 0.f;
#pragma unroll
      for (int j = 0; j < 4; ++j) { p[j] = __expf(s[i][j] - mnew); rs += p[j]; }
#pragma unroll
      for (int mm = 1; mm < 16; mm <<= 1) rs += __shfl_xor(rs, mm);
      l_i[i] = l_i[i] * sc + rs;
      m_i[i] = mnew;
#pragma unroll
      for (int j = 0; j < 4; ++j) o[i][j] *= sc;
      *(float4*)&Ps[tr * 4 + i][tc * 4] = *(float4*)p;
    }
    __syncthreads();

#pragma unroll 4
    for (int j = 0; j < 64; ++j) {
      float vv[4];
      *(float4*)vv = *(const float4*)&Vs[j][tc * 4];
      float pj[4];
#pragma unroll
      for (int i = 0; i < 4; ++i) pj[i] = Ps[tr * 4 + i][j];
#pragma unroll
      for (int i = 0; i < 4; ++i)
#pragma unroll
        for (int dj = 0; dj < 4; ++dj) o[i][dj] += pj[i] * vv[dj];
    }
  }

#pragma unroll
  for (int i = 0; i < 4; ++i) {
    float inv = 1.f / l_i[i];
    ushort4 rb;
    rb.x = f2bf(o[i][0] * inv); rb.y = f2bf(o[i][1] * inv);
    rb.z = f2bf(o[i][2] * inv); rb.w = f2bf(o[i][3] * inv);
    *(ushort4*)(ctxb + (size_t)(b * SEQ + q0 + tr * 4 + i) * DM + hh * 64 + tc * 4) = rb;
  }
}

// ---------------- out = LayerNorm(X + Y); optional bf16 copy ----------------
template<int DUAL>
__global__ __launch_bounds__(256)
void add_ln_kernel(const float* __restrict__ X, const float* __restrict__ Y,
                   const float* __restrict__ g, const float* __restrict__ be,
                   float* __restrict__ out, unsigned short* __restrict__ outb)
{
  __shared__ float red[8];
  const int row = blockIdx.x;
  const int tid = threadIdx.x;
  const size_t off = (size_t)row * DM + tid * 4;
  float4 xv = *(const float4*)(X + off);
  float4 yv = *(const float4*)(Y + off);
  float v0 = xv.x + yv.x, v1 = xv.y + yv.y, v2 = xv.z + yv.z, v3 = xv.w + yv.w;
  float s = v0 + v1 + v2 + v3;
#pragma unroll
  for (int m = 1; m < 64; m <<= 1) s += __shfl_xor(s, m);
  if ((tid & 63) == 0) red[tid >> 6] = s;
  __syncthreads();
  float mean = (red[0] + red[1] + red[2] + red[3]) * (1.f / DM);
  float d0 = v0 - mean, d1 = v1 - mean, d2 = v2 - mean, d3 = v3 - mean;
  float sq = d0 * d0 + d1 * d1 + d2 * d2 + d3 * d3;
#pragma unroll
  for (int m = 1; m < 64; m <<= 1) sq += __shfl_xor(sq, m);
  if ((tid & 63) == 0) red[4 + (tid >> 6)] = sq;
  __syncthreads();
  float var = (red[4] + red[5] + red[6] + red[7]) * (1.f / DM);
  float inv = rsqrtf(var + EPSF);
  int col = tid * 4;
  float4 r;
  r.x = d0 * inv * g[col + 0] + be[col + 0];
  r.y = d1 * inv * g[col + 1] + be[col + 1];
  r.z = d2 * inv * g[col + 2] + be[col + 2];
  r.w = d3 * inv * g[col + 3] + be[col + 3];
  *(float4*)(out + off) = r;
  if (DUAL) {
    ushort4 rb;
    rb.x = f2bf(r.x); rb.y = f2bf(r.y); rb.z = f2bf(r.z); rb.w = f2bf(r.w);
    *(ushort4*)(outb + off) = rb;
  }
}

extern "C" void kernel_launch(void* const* d_in, const int* in_sizes, int n_in,
                              void* d_out, int out_size, void* d_ws, size_t ws_size,
                              hipStream_t stream)
{
  const float* x    = (const float*)d_in[0];
  const float* mask = (const float*)d_in[1];
  const float* wq   = (const float*)d_in[2];
  const float* bq   = (const float*)d_in[3];
  const float* wk   = (const float*)d_in[4];
  const float* bk   = (const float*)d_in[5];
  const float* wv   = (const float*)d_in[6];
  const float* bv   = (const float*)d_in[7];
  const float* wo   = (const float*)d_in[8];
  const float* bo   = (const float*)d_in[9];
  const float* w1   = (const float*)d_in[10];
  const float* b1   = (const float*)d_in[11];
  const float* w2   = (const float*)d_in[12];
  const float* b2   = (const float*)d_in[13];
  const float* g1   = (const float*)d_in[14];
  const float* be1  = (const float*)d_in[15];
  const float* g2   = (const float*)d_in[16];
  const float* be2  = (const float*)d_in[17];
  float* out = (float*)d_out;
  char* wsb = (char*)d_ws;

  float* q = (float*)(wsb);                      // -> attn_out -> ffn
  float* k = (float*)(wsb + (32u << 20));        // -> out1
  float* v = (float*)(wsb + (64u << 20));        // -> hbuf
  unsigned short* ctxb = (unsigned short*)(wsb + (96u << 20));   // -> out1b
  unsigned short* xb   = (unsigned short*)(wsb + (112u << 20));
  unsigned short* wqt  = (unsigned short*)(wsb + (128u << 20));
  unsigned short* wkt  = (unsigned short*)(wsb + (130u << 20));
  unsigned short* wvt  = (unsigned short*)(wsb + (132u << 20));
  unsigned short* wot  = (unsigned short*)(wsb + (134u << 20));
  unsigned short* w1t  = (unsigned short*)(wsb + (136u << 20));
  unsigned short* w2t  = (unsigned short*)(wsb + (144u << 20));
  float* attn_out = q;
  float* out1     = k;
  unsigned short* out1b = ctxb;
  unsigned short* hbuf  = (unsigned short*)v;
  float* ffn = q;

  dim3 blk(256);

  convert_bf16<<<8192, blk, 0, stream>>>(x, xb, (BATCH * SEQ * DM) / 4);
  transpose_to_bf16<<<dim3(32, 32), blk, 0, stream>>>(wq, wqt, DM, DM);
  transpose_to_bf16<<<dim3(32, 32), blk, 0, stream>>>(wk, wkt, DM, DM);
  transpose_to_bf16<<<dim3(32, 32), blk, 0, stream>>>(wv, wvt, DM, DM);
  transpose_to_bf16<<<dim3(32, 32), blk, 0, stream>>>(wo, wot, DM, DM);
  transpose_to_bf16<<<dim3(128, 32), blk, 0, stream>>>(w1, w1t, DM, DFF_);
  transpose_to_bf16<<<dim3(32, 128), blk, 0, stream>>>(w2, w2t, DFF_, DM);

  const int M = BATCH * SEQ;   // 8192
  gemm_mfma<0, 1, 0><<<dim3(8, 64), blk, 0, stream>>>(xb, wqt, bq, q, nullptr, M, DM, DM);
  gemm_mfma<0, 1, 0><<<dim3(8, 64), blk, 0, stream>>>(xb, wkt, bk, k, nullptr, M, DM, DM);
  gemm_mfma<0, 1, 0><<<dim3(8, 64), blk, 0, stream>>>(xb, wvt, bv, v, nullptr, M, DM, DM);

  attn_kernel<<<dim3(SEQ / 64, BATCH * NH), blk, 0, stream>>>(q, k, v, mask, ctxb);

  gemm_mfma<0, 0, 0><<<dim3(8, 64), blk, 0, stream>>>(ctxb, wot, bo, attn_out, nullptr, M, DM, DM);
  add_ln_kernel<1><<<dim3(M), blk, 0, stream>>>(x, attn_out, g1, be1, out1, out1b);

  for (int c = 0; c < 2; ++c) {
    gemm_mfma<1, 0, 1><<<dim3(32, 32), blk, 0, stream>>>(
        out1b + (size_t)c * 4096 * DM, w1t, b1, nullptr, hbuf, 4096, DFF_, DM);
    gemm_mfma<0, 0, 0><<<dim3(8, 32), blk, 0, stream>>>(
        hbuf, w2t, b2, ffn + (size_t)c * 4096 * DM, nullptr, 4096, DM, DFF_);
  }
  add_ln_kernel<0><<<dim3(M), blk, 0, stream>>>(out1, ffn, g2, be2, out, nullptr);
}

// Round 4
// 767.101 us; speedup vs baseline: 4.7923x; 2.1758x over previous
//
#include <hip/hip_runtime.h>
#include <cstdint>

// Transformer encoder layer. bf16-MFMA GEMMs + bf16-MFMA flash attention.
// B=4 S=2048 D=1024 H=16 depth=64 DFF=4096.
//
// Workspace layout (MB offsets, total 136 MB):
//   [0,16)    qb bf16 [B,H,S,64]      -> attn_out fp32 [0,32) -> ffn fp32 [0,32)
//   [16,32)   kb bf16 [B,H,S,64]
//   [32,48)   vtb bf16 [B,H,64,S]     -> out1 fp32 [32,64)
//   [48,64)   ctxb bf16 [B,S,D]
//   [64,80)   xb bf16                 -> out1b bf16
//   [80,112)  hbuf bf16 (4096x4096 FFN hidden, per chunk)
//   [112,136) weights: wqt,wkt,wvt,wot (2 each), w1t (8), w2t (8)

#define BATCH 4
#define SEQ   2048
#define DM    1024
#define NH    16
#define DEPTH 64
#define DFF_  4096
#define EPSF  1e-6f

typedef short bf16x8 __attribute__((ext_vector_type(8)));
typedef float f32x4  __attribute__((ext_vector_type(4)));

__device__ __forceinline__ unsigned short f2bf(float f) {
  union { float f; unsigned int u; } v; v.f = f;
  unsigned int u = v.u;
  return (unsigned short)((u + 0x7fffu + ((u >> 16) & 1u)) >> 16);  // RNE
}

__device__ __forceinline__ void gload_lds16(const void* g, void* l) {
  __builtin_amdgcn_global_load_lds(
      (const __attribute__((address_space(1))) unsigned int*)g,
      (__attribute__((address_space(3))) unsigned int*)l, 16, 0, 0);
}

// ---------------- bf16 MFMA GEMM: C = act(A @ Bt^T + bias) ----------------
// A:[M,K] bf16 row-major. Bt:[N,K] bf16 row-major (pre-transposed weight).
// 128x128 tile, BK=32, 4 waves (2x2), each wave 64x64 = 4x4 frags of 16x16x32.
// SPLIT=0: C fp32/bf16 [M,N]. SPLIT=1: bf16 [B,H,S,64]. SPLIT=2: bf16 [B,H,64,S].
template<int ACT, int SPLIT, int OUT_BF16>
__global__ __launch_bounds__(256)
void gemm_mfma(const unsigned short* __restrict__ A, const unsigned short* __restrict__ Bt,
               const float* __restrict__ bias, float* __restrict__ Cf,
               unsigned short* __restrict__ Cb, int M, int N, int K)
{
  __shared__ unsigned short As[128 * 32];
  __shared__ unsigned short Bs[128 * 32];
  const int tid  = threadIdx.x;
  const int wid  = tid >> 6;
  const int lane = tid & 63;
  const int wr = wid >> 1, wc = wid & 1;
  const int m0 = blockIdx.y * 128;
  const int n0 = blockIdx.x * 128;

  const int lrow   = lane >> 2;                    // staging: row within 16-row seg
  const int lchunk = (lane & 3) ^ (lrow & 3);      // inverse-swizzled source chunk
  const int fr = lane & 15;                        // fragment row/col
  const int kh = lane >> 4;                        // k-quarter (8 bf16 each)

  f32x4 acc[4][4] = {};

  const char* gA = (const char*)A;
  const char* gB = (const char*)Bt;
  char* lA = (char*)As;
  char* lB = (char*)Bs;

  for (int k0 = 0; k0 < K; k0 += 32) {
#pragma unroll
    for (int seg = 0; seg < 2; ++seg) {
      int r = wid * 32 + seg * 16 + lrow;          // tile row staged by this lane
      gload_lds16(gA + ((size_t)(m0 + r) * K + k0) * 2 + lchunk * 16,
                  lA + (wid * 32 + seg * 16) * 64);
      gload_lds16(gB + ((size_t)(n0 + r) * K + k0) * 2 + lchunk * 16,
                  lB + (wid * 32 + seg * 16) * 64);
    }
    __syncthreads();   // compiler drains vmcnt before s_barrier
    bf16x8 af[4], bg[4];
#pragma unroll
    for (int i = 0; i < 4; ++i) {
      af[i] = *(const bf16x8*)(lA + (wr * 64 + i * 16 + fr) * 64 + ((kh ^ (fr & 3)) * 16));
      bg[i] = *(const bf16x8*)(lB + (wc * 64 + i * 16 + fr) * 64 + ((kh ^ (fr & 3)) * 16));
    }
#pragma unroll
    for (int i = 0; i < 4; ++i)
#pragma unroll
      for (int j = 0; j < 4; ++j)
        acc[i][j] = __builtin_amdgcn_mfma_f32_16x16x32_bf16(af[i], bg[j], acc[i][j], 0, 0, 0);
    __syncthreads();
  }

  // epilogue: C/D layout col=lane&15, row=(lane>>4)*4+reg  [m89/m91]
  const int rbase = (lane >> 4) * 4;
  const int ccol  = lane & 15;
  float bcol[4];
#pragma unroll
  for (int j = 0; j < 4; ++j) bcol[j] = bias[n0 + wc * 64 + j * 16 + ccol];
#pragma unroll
  for (int i = 0; i < 4; ++i)
#pragma unroll
    for (int jj = 0; jj < 4; ++jj) {
      int row = m0 + wr * 64 + i * 16 + rbase + jj;
#pragma unroll
      for (int j = 0; j < 4; ++j) {
        float vv = acc[i][j][jj] + bcol[j];
        if (ACT) vv = fmaxf(vv, 0.f);
        int col = n0 + wc * 64 + j * 16 + ccol;
        if (SPLIT == 1) {        // bf16 [B,H,S,DEPTH]
          int b = row >> 11, s = row & (SEQ - 1);
          int hh = col >> 6, d = col & 63;
          Cb[(((size_t)(b * NH + hh)) * SEQ + s) * DEPTH + d] = f2bf(vv);
        } else if (SPLIT == 2) { // bf16 [B,H,DEPTH,S]  (V transposed)
          int b = row >> 11, s = row & (SEQ - 1);
          int hh = col >> 6, d = col & 63;
          Cb[(((size_t)(b * NH + hh)) * DEPTH + d) * SEQ + s] = f2bf(vv);
        } else if (OUT_BF16) {
          Cb[(size_t)row * N + col] = f2bf(vv);
        } else {
          Cf[(size_t)row * N + col] = vv;
        }
      }
    }
}

// ---------------- weight fp32 [K,N] -> bf16 [N,K] transpose ----------------
__global__ __launch_bounds__(256)
void transpose_to_bf16(const float* __restrict__ W, unsigned short* __restrict__ Wt,
                       int K, int N)
{
  __shared__ float t[32][33];
  const int tx = threadIdx.x & 31;
  const int ty = threadIdx.x >> 5;      // 0..7
  const int n0 = blockIdx.x * 32;
  const int k0 = blockIdx.y * 32;
#pragma unroll
  for (int i = 0; i < 4; ++i) {
    int r = ty + i * 8;
    t[r][tx] = W[(size_t)(k0 + r) * N + n0 + tx];
  }
  __syncthreads();
#pragma unroll
  for (int i = 0; i < 4; ++i) {
    int r = ty + i * 8;
    Wt[(size_t)(n0 + r) * K + k0 + tx] = f2bf(t[tx][r]);
  }
}

// ---------------- fp32 -> bf16 elementwise ----------------
__global__ __launch_bounds__(256)
void convert_bf16(const float* __restrict__ X, unsigned short* __restrict__ Xb, int n4)
{
  int i = blockIdx.x * 256 + threadIdx.x;
  if (i < n4) {
    float4 v = ((const float4*)X)[i];
    ushort4 r;
    r.x = f2bf(v.x); r.y = f2bf(v.y); r.z = f2bf(v.z); r.w = f2bf(v.w);
    ((ushort4*)Xb)[i] = r;
  }
}

// ---------------- bf16 MFMA flash attention ----------------
// Q,K: [B,H,S,64] bf16; Vt: [B,H,64,S] bf16; ctx out: [B,S,D] bf16.
// Grid (S/64, B*H), 256 thr (4 waves x 16 q-rows). KV tile = 64.
// Swapped mfma: S[kv][q] (q = lane&15), O[d][q] — softmax state lane-local per q.
// K/Vt tiles: 128-B rows, 8x16B chunks, chunk c of row r holds global chunk c^(r&7).
__global__ __launch_bounds__(256)
void attn_mfma(const unsigned short* __restrict__ Qb, const unsigned short* __restrict__ Kb,
               const unsigned short* __restrict__ Vtb, const float* __restrict__ mask,
               unsigned short* __restrict__ ctxb)
{
  __shared__ unsigned short Ks[64 * 64];      // [kv][d] swizzled, 8 KB
  __shared__ unsigned short Vts[64 * 64];     // [d][kv] swizzled, 8 KB
  __shared__ unsigned short Ps[4][16 * 72];   // per-wave P [16 q][72 kv-pad], 9.2 KB
  __shared__ float Ms[SEQ];                   // mask row for b, 8 KB

  const int tid  = threadIdx.x;
  const int w    = tid >> 6;
  const int lane = tid & 63;
  const int fr   = lane & 15;                 // = q within wave (ccol) = frag row
  const int kh   = lane >> 4;
  const int rbase = kh * 4;
  const int bh = blockIdx.y;
  const int b  = bh >> 4, hh = bh & 15;
  const int q0 = blockIdx.x * 64;

  // stage mask row for this batch
  for (int i = tid; i < SEQ / 4; i += 256)
    *(float4*)&Ms[i * 4] = *(const float4*)&mask[(size_t)b * SEQ + i * 4];

  // Q fragments for this wave's 16 q-rows (held in registers all kernel)
  const size_t qrow = ((size_t)bh * SEQ + q0 + w * 16 + fr) * DEPTH;
  bf16x8 bq[2];
  bq[0] = *(const bf16x8*)(Qb + qrow + kh * 8);
  bq[1] = *(const bf16x8*)(Qb + qrow + 32 + kh * 8);

  float m_run = -1e30f, l_run = 0.f;
  f32x4 o[4] = {};                            // O[d=16db+rbase+jj][q=fr]

  const int stg_chunk = (lane & 7) ^ (lane >> 3);   // inverse-swizzled source chunk
  const int r8 = lane >> 3;                         // row within 8-row staging group
  unsigned short* Pw = &Ps[w][0];

  for (int kv0 = 0; kv0 < SEQ; kv0 += 64) {
    __syncthreads();   // prev-tile readers done (iter 0: also fences mask staging)
#pragma unroll
    for (int i = 0; i < 2; ++i) {
      int rr = w * 16 + i * 8 + r8;           // tile row this lane sources
      gload_lds16((const char*)Kb + (((size_t)bh * SEQ + kv0 + rr) * DEPTH) * 2 + stg_chunk * 16,
                  (char*)Ks + (w * 16 + i * 8) * 128);
      gload_lds16((const char*)Vtb + (((size_t)bh * DEPTH + rr) * SEQ + kv0) * 2 + stg_chunk * 16,
                  (char*)Vts + (w * 16 + i * 8) * 128);
    }
    __syncthreads();   // staging complete (vmcnt drained before barrier)

    // QK^T (swapped): S[kv=16j+rbase+jj][q=fr]
    f32x4 s[4] = {};
#pragma unroll
    for (int ks = 0; ks < 2; ++ks)
#pragma unroll
      for (int j = 0; j < 4; ++j) {
        bf16x8 ak = *(const bf16x8*)((const char*)Ks + (j * 16 + fr) * 128 +
                                     (((ks * 4 + kh) ^ (fr & 7)) * 16));
        s[j] = __builtin_amdgcn_mfma_f32_16x16x32_bf16(ak, bq[ks], s[j], 0, 0, 0);
      }

    // scale + mask; online softmax (row q entirely in the 4 kh-lanes)
    float p[16];
    float pmax = -1e30f;
#pragma unroll
    for (int j = 0; j < 4; ++j) {
      float4 mk = *(const float4*)&Ms[kv0 + j * 16 + rbase];
#pragma unroll
      for (int jj = 0; jj < 4; ++jj) {
        float vsc = s[j][jj] * 0.125f + ((const float*)&mk)[jj] * (-1e9f);
        p[j * 4 + jj] = vsc;
        pmax = fmaxf(pmax, vsc);
      }
    }
    pmax = fmaxf(pmax, __shfl_xor(pmax, 16));
    pmax = fmaxf(pmax, __shfl_xor(pmax, 32));
    float mnew = fmaxf(m_run, pmax);
    float sc = __expf(m_run - mnew);
    float rs = 0.f;
#pragma unroll
    for (int t = 0; t < 16; ++t) { p[t] = __expf(p[t] - mnew); rs += p[t]; }
    rs += __shfl_xor(rs, 16);
    rs += __shfl_xor(rs, 32);
    l_run = l_run * sc + rs;
    m_run = mnew;
#pragma unroll
    for (int db = 0; db < 4; ++db) {
      o[db][0] *= sc; o[db][1] *= sc; o[db][2] *= sc; o[db][3] *= sc;
    }

    // P -> per-wave LDS (bf16, padded rows of 144 B), then read as B-frags
#pragma unroll
    for (int j = 0; j < 4; ++j) {
      unsigned int lo = (unsigned)f2bf(p[j * 4 + 0]) | ((unsigned)f2bf(p[j * 4 + 1]) << 16);
      unsigned int hi = (unsigned)f2bf(p[j * 4 + 2]) | ((unsigned)f2bf(p[j * 4 + 3]) << 16);
      unsigned long long pk = (unsigned long long)lo | ((unsigned long long)hi << 32);
      *(unsigned long long*)((char*)Pw + fr * 144 + (j * 16 + rbase) * 2) = pk;
    }
    // PV (swapped): O[d][q] += Vt x P
#pragma unroll
    for (int ks = 0; ks < 2; ++ks) {
      bf16x8 bp = *(const bf16x8*)((char*)Pw + fr * 144 + ks * 64 + kh * 16);
#pragma unroll
      for (int db = 0; db < 4; ++db) {
        bf16x8 av = *(const bf16x8*)((const char*)Vts + (db * 16 + fr) * 128 +
                                     (((ks * 4 + kh) ^ (fr & 7)) * 16));
        o[db] = __builtin_amdgcn_mfma_f32_16x16x32_bf16(av, bp, o[db], 0, 0, 0);
      }
    }
  }

  // normalize + write ctx [B,S,D] bf16: row = q0+w*16+fr, cols hh*64 + 16db+rbase+jj
  float inv = 1.f / l_run;
  const int srow = q0 + w * 16 + fr;
#pragma unroll
  for (int db = 0; db < 4; ++db) {
    ushort4 rb;
    rb.x = f2bf(o[db][0] * inv); rb.y = f2bf(o[db][1] * inv);
    rb.z = f2bf(o[db][2] * inv); rb.w = f2bf(o[db][3] * inv);
    *(ushort4*)(ctxb + ((size_t)(b * SEQ + srow)) * DM + hh * 64 + db * 16 + rbase) = rb;
  }
}

// ---------------- out = LayerNorm(X + Y); optional bf16 copy ----------------
template<int DUAL>
__global__ __launch_bounds__(256)
void add_ln_kernel(const float* __restrict__ X, const float* __restrict__ Y,
                   const float* __restrict__ g, const float* __restrict__ be,
                   float* __restrict__ out, unsigned short* __restrict__ outb)
{
  __shared__ float red[8];
  const int row = blockIdx.x;
  const int tid = threadIdx.x;
  const size_t off = (size_t)row * DM + tid * 4;
  float4 xv = *(const float4*)(X + off);
  float4 yv = *(const float4*)(Y + off);
  float v0 = xv.x + yv.x, v1 = xv.y + yv.y, v2 = xv.z + yv.z, v3 = xv.w + yv.w;
  float s = v0 + v1 + v2 + v3;
#pragma unroll
  for (int m = 1; m < 64; m <<= 1) s += __shfl_xor(s, m);
  if ((tid & 63) == 0) red[tid >> 6] = s;
  __syncthreads();
  float mean = (red[0] + red[1] + red[2] + red[3]) * (1.f / DM);
  float d0 = v0 - mean, d1 = v1 - mean, d2 = v2 - mean, d3 = v3 - mean;
  float sq = d0 * d0 + d1 * d1 + d2 * d2 + d3 * d3;
#pragma unroll
  for (int m = 1; m < 64; m <<= 1) sq += __shfl_xor(sq, m);
  if ((tid & 63) == 0) red[4 + (tid >> 6)] = sq;
  __syncthreads();
  float var = (red[4] + red[5] + red[6] + red[7]) * (1.f / DM);
  float inv = rsqrtf(var + EPSF);
  int col = tid * 4;
  float4 r;
  r.x = d0 * inv * g[col + 0] + be[col + 0];
  r.y = d1 * inv * g[col + 1] + be[col + 1];
  r.z = d2 * inv * g[col + 2] + be[col + 2];
  r.w = d3 * inv * g[col + 3] + be[col + 3];
  *(float4*)(out + off) = r;
  if (DUAL) {
    ushort4 rb;
    rb.x = f2bf(r.x); rb.y = f2bf(r.y); rb.z = f2bf(r.z); rb.w = f2bf(r.w);
    *(ushort4*)(outb + off) = rb;
  }
}

extern "C" void kernel_launch(void* const* d_in, const int* in_sizes, int n_in,
                              void* d_out, int out_size, void* d_ws, size_t ws_size,
                              hipStream_t stream)
{
  const float* x    = (const float*)d_in[0];
  const float* mask = (const float*)d_in[1];
  const float* wq   = (const float*)d_in[2];
  const float* bq   = (const float*)d_in[3];
  const float* wk   = (const float*)d_in[4];
  const float* bk   = (const float*)d_in[5];
  const float* wv   = (const float*)d_in[6];
  const float* bv   = (const float*)d_in[7];
  const float* wo   = (const float*)d_in[8];
  const float* bo   = (const float*)d_in[9];
  const float* w1   = (const float*)d_in[10];
  const float* b1   = (const float*)d_in[11];
  const float* w2   = (const float*)d_in[12];
  const float* b2   = (const float*)d_in[13];
  const float* g1   = (const float*)d_in[14];
  const float* be1  = (const float*)d_in[15];
  const float* g2   = (const float*)d_in[16];
  const float* be2  = (const float*)d_in[17];
  float* out = (float*)d_out;
  char* wsb = (char*)d_ws;

  unsigned short* qb   = (unsigned short*)(wsb);                 // [0,16)
  unsigned short* kb   = (unsigned short*)(wsb + (16u << 20));   // [16,32)
  unsigned short* vtb  = (unsigned short*)(wsb + (32u << 20));   // [32,48)
  unsigned short* ctxb = (unsigned short*)(wsb + (48u << 20));   // [48,64)
  unsigned short* xb   = (unsigned short*)(wsb + (64u << 20));   // [64,80)
  unsigned short* hbuf = (unsigned short*)(wsb + (80u << 20));   // [80,112)
  unsigned short* wqt  = (unsigned short*)(wsb + (112u << 20));
  unsigned short* wkt  = (unsigned short*)(wsb + (114u << 20));
  unsigned short* wvt  = (unsigned short*)(wsb + (116u << 20));
  unsigned short* wot  = (unsigned short*)(wsb + (118u << 20));
  unsigned short* w1t  = (unsigned short*)(wsb + (120u << 20));
  unsigned short* w2t  = (unsigned short*)(wsb + (128u << 20));
  float* attn_out = (float*)(wsb);                 // [0,32)  after attention
  float* out1     = (float*)(wsb + (32u << 20));   // [32,64) after WO+LN1
  unsigned short* out1b = xb;                      // [64,80) after LN1
  float* ffn      = (float*)(wsb);                 // [0,32)  after LN1

  dim3 blk(256);

  convert_bf16<<<8192, blk, 0, stream>>>(x, xb, (BATCH * SEQ * DM) / 4);
  transpose_to_bf16<<<dim3(32, 32), blk, 0, stream>>>(wq, wqt, DM, DM);
  transpose_to_bf16<<<dim3(32, 32), blk, 0, stream>>>(wk, wkt, DM, DM);
  transpose_to_bf16<<<dim3(32, 32), blk, 0, stream>>>(wv, wvt, DM, DM);
  transpose_to_bf16<<<dim3(32, 32), blk, 0, stream>>>(wo, wot, DM, DM);
  transpose_to_bf16<<<dim3(128, 32), blk, 0, stream>>>(w1, w1t, DM, DFF_);
  transpose_to_bf16<<<dim3(32, 128), blk, 0, stream>>>(w2, w2t, DFF_, DM);

  const int M = BATCH * SEQ;   // 8192
  gemm_mfma<0, 1, 0><<<dim3(8, 64), blk, 0, stream>>>(xb, wqt, bq, nullptr, qb, M, DM, DM);
  gemm_mfma<0, 1, 0><<<dim3(8, 64), blk, 0, stream>>>(xb, wkt, bk, nullptr, kb, M, DM, DM);
  gemm_mfma<0, 2, 0><<<dim3(8, 64), blk, 0, stream>>>(xb, wvt, bv, nullptr, vtb, M, DM, DM);

  attn_mfma<<<dim3(SEQ / 64, BATCH * NH), blk, 0, stream>>>(qb, kb, vtb, mask, ctxb);

  gemm_mfma<0, 0, 0><<<dim3(8, 64), blk, 0, stream>>>(ctxb, wot, bo, attn_out, nullptr, M, DM, DM);
  add_ln_kernel<1><<<dim3(M), blk, 0, stream>>>(x, attn_out, g1, be1, out1, out1b);

  for (int c = 0; c < 2; ++c) {
    gemm_mfma<1, 0, 1><<<dim3(32, 32), blk, 0, stream>>>(
        out1b + (size_t)c * 4096 * DM, w1t, b1, nullptr, hbuf, 4096, DFF_, DM);
    gemm_mfma<0, 0, 0><<<dim3(8, 32), blk, 0, stream>>>(
        hbuf, w2t, b2, ffn + (size_t)c * 4096 * DM, nullptr, 4096, DM, DFF_);
  }
  add_ln_kernel<0><<<dim3(M), blk, 0, stream>>>(out1, ffn, g2, be2, out, nullptr);
}

// Round 5
// 636.363 us; speedup vs baseline: 5.7768x; 1.2054x over previous
//
#include <hip/hip_runtime.h>
#include <cstdint>

// Transformer encoder layer. 8-phase 256x256 bf16-MFMA GEMMs + bf16-MFMA flash attention.
// B=4 S=2048 D=1024 H=16 depth=64 DFF=4096.
//
// Workspace layout (MB offsets, total 168 MB; 192 MB proven available in round 1):
//   [0,16)    qb bf16 [B,H,S,64]     -> attn_out fp32 [0,32) -> ffn fp32 [0,32)
//   [16,32)   kb bf16 [B,H,S,64]
//   [32,48)   vtb bf16 [B,H,64,S]    -> out1 fp32 [32,64)
//   [48,64)   ctxb bf16 [B,S,D]
//   [64,80)   xb bf16                -> out1b bf16
//   [80,144)  hbuf bf16 [8192,4096]
//   [144,150) wqkvt bf16 [3072,1024]
//   [150,152) wot bf16 [1024,1024]
//   [152,160) w1t bf16 [4096,1024]
//   [160,168) w2t bf16 [1024,4096]

#define BATCH 4
#define SEQ   2048
#define DM    1024
#define NH    16
#define DEPTH 64
#define DFF_  4096
#define EPSF  1e-6f

typedef short bf16x8 __attribute__((ext_vector_type(8)));
typedef float f32x4  __attribute__((ext_vector_type(4)));

__device__ __forceinline__ unsigned short f2bf(float f) {
  union { float f; unsigned int u; } v; v.f = f;
  unsigned int u = v.u;
  return (unsigned short)((u + 0x7fffu + ((u >> 16) & 1u)) >> 16);  // RNE
}

__device__ __forceinline__ void gload_lds16(const void* g, void* l) {
  __builtin_amdgcn_global_load_lds(
      (const __attribute__((address_space(1))) unsigned int*)g,
      (__attribute__((address_space(3))) unsigned int*)l, 16, 0, 0);
}

#define VMCNT(n) asm volatile("s_waitcnt vmcnt(" #n ")" ::: "memory")

// ---------------- 8-phase 256x256 bf16 MFMA GEMM ----------------
// A:[M,K] bf16 row-major. Bt:[N,K] bf16 row-major. 512 threads = 8 waves (2M x 4N),
// wave tile 128x64 (acc 8x4 frags of 16x16x32). BK=64, LDS 2 x (A 32K + B 32K) = 128 KiB.
// LDS rows 128 B; 16B-chunk c of row r holds global chunk c^(r&7) (both-sides swizzle).
// Staging: 8 x 8KB regions per K-tile (B0 B1 | B2 B3 | A0 A2 | A1 A3 over phases 0-3 of
// the PREVIOUS tile), counted vmcnt(4) @end-p1 (secures A1,A3 of current tile) and
// vmcnt(2) @end-p3 (secures B*,A0,A2 of next tile); waits always precede a barrier so
// per-wave vmcnt composes to an all-waves guarantee.
// EPI: 0 = fp32 [M,N] + bias; 1 = relu bf16 [M,N] + bias; 2 = fused QKV scatter.
template<int EPI>
__global__ __launch_bounds__(512, 2)
void gemm8(const unsigned short* __restrict__ A, const unsigned short* __restrict__ Bt,
           const float* __restrict__ bias0, const float* __restrict__ bias1,
           const float* __restrict__ bias2, float* __restrict__ Cf,
           unsigned short* __restrict__ Cb0, unsigned short* __restrict__ Cb1,
           unsigned short* __restrict__ Cb2, int M, int N, int K)
{
  __shared__ char smem[131072];
  const int tid  = threadIdx.x;
  const int lane = tid & 63;
  const int wid  = tid >> 6;
  const int wr   = wid >> 2;          // 0..1  (M half)
  const int wcn  = wid & 3;           // 0..3  (N quarter)
  const int fr   = lane & 15;
  const int kh   = lane >> 4;

  // XCD-aware block swizzle (all our grids are %8==0)
  const int nbx  = N >> 8;
  const int nwg  = gridDim.x;
  const int flat = blockIdx.x;
  const int swz  = (flat & 7) * (nwg >> 3) + (flat >> 3);
  const int bx = swz % nbx, by = swz / nbx;
  const int m0 = by << 8, n0 = bx << 8;

  // staging constants: region = 64 rows x 128 B = 8 KB, 1 gload_lds/thread
  const int lr  = tid >> 3;           // 0..63 local row
  const int ch  = tid & 7;            // dest chunk
  const int sch = ch ^ (lr & 7);      // inverse-swizzled source chunk
  const char* gA = (const char*)A + ((size_t)(m0 + lr) * K) * 2 + sch * 16;
  const char* gB = (const char*)Bt + ((size_t)(n0 + lr) * K) * 2 + sch * 16;
  const size_t rstep = (size_t)K * 128;   // 64 rows * K * 2B

  // LDS read constants
  const int chk0 = ((kh) ^ (fr & 7)) * 16;
  const int chk1 = ((4 + kh) ^ (fr & 7)) * 16;
  const int rowA = wr * 128 + fr;
  const int rowB = wcn * 64 + fr;

  f32x4 acc[8][4] = {};
  bf16x8 bg[4][2];
  const int NT = K >> 6;

  // prologue: stage tile 0 into buf0 (order B0 B1 B2 B3 A0 A2 A1 A3)
  {
    char* sb = smem;
    gload_lds16(gB + 0 * rstep, sb + 32768 + 0 * 8192 + tid * 16);
    gload_lds16(gB + 1 * rstep, sb + 32768 + 1 * 8192 + tid * 16);
    gload_lds16(gB + 2 * rstep, sb + 32768 + 2 * 8192 + tid * 16);
    gload_lds16(gB + 3 * rstep, sb + 32768 + 3 * 8192 + tid * 16);
    gload_lds16(gA + 0 * rstep, sb + 0 * 8192 + tid * 16);
    gload_lds16(gA + 2 * rstep, sb + 2 * 8192 + tid * 16);
    gload_lds16(gA + 1 * rstep, sb + 1 * 8192 + tid * 16);
    gload_lds16(gA + 3 * rstep, sb + 3 * 8192 + tid * 16);
    VMCNT(2);                    // retire B*,A0,A2; leave A1,A3 in flight
    __builtin_amdgcn_s_barrier();
  }

  for (int t = 0; t < NT - 1; ++t) {
    char* rb = smem + ((t & 1) << 16);
    char* sb = smem + (((t + 1) & 1) << 16);
    const size_t kg = (size_t)(t + 1) * 128;   // next K-tile byte offset (64 elem * 2B)
#pragma unroll
    for (int p = 0; p < 4; ++p) {
      // stage 2 regions of tile t+1
      if (p == 0) {
        gload_lds16(gB + kg + 0 * rstep, sb + 32768 + 0 * 8192 + tid * 16);
        gload_lds16(gB + kg + 1 * rstep, sb + 32768 + 1 * 8192 + tid * 16);
      } else if (p == 1) {
        gload_lds16(gB + kg + 2 * rstep, sb + 32768 + 2 * 8192 + tid * 16);
        gload_lds16(gB + kg + 3 * rstep, sb + 32768 + 3 * 8192 + tid * 16);
      } else if (p == 2) {
        gload_lds16(gA + kg + 0 * rstep, sb + 0 * 8192 + tid * 16);
        gload_lds16(gA + kg + 2 * rstep, sb + 2 * 8192 + tid * 16);
      } else {
        gload_lds16(gA + kg + 1 * rstep, sb + 1 * 8192 + tid * 16);
        gload_lds16(gA + kg + 3 * rstep, sb + 3 * 8192 + tid * 16);
      }
      // ds_reads (B once per tile at p==0; A pair per phase)
      if (p == 0) {
#pragma unroll
        for (int j = 0; j < 4; ++j) {
          bg[j][0] = *(const bf16x8*)(rb + 32768 + (rowB + j * 16) * 128 + chk0);
          bg[j][1] = *(const bf16x8*)(rb + 32768 + (rowB + j * 16) * 128 + chk1);
        }
      }
      bf16x8 a00 = *(const bf16x8*)(rb + (rowA + (2 * p) * 16) * 128 + chk0);
      bf16x8 a01 = *(const bf16x8*)(rb + (rowA + (2 * p) * 16) * 128 + chk1);
      bf16x8 a10 = *(const bf16x8*)(rb + (rowA + (2 * p + 1) * 16) * 128 + chk0);
      bf16x8 a11 = *(const bf16x8*)(rb + (rowA + (2 * p + 1) * 16) * 128 + chk1);
      __builtin_amdgcn_s_barrier();
      __builtin_amdgcn_s_setprio(1);
#pragma unroll
      for (int j = 0; j < 4; ++j) {
        acc[2*p][j]   = __builtin_amdgcn_mfma_f32_16x16x32_bf16(a00, bg[j][0], acc[2*p][j], 0, 0, 0);
        acc[2*p][j]   = __builtin_amdgcn_mfma_f32_16x16x32_bf16(a01, bg[j][1], acc[2*p][j], 0, 0, 0);
        acc[2*p+1][j] = __builtin_amdgcn_mfma_f32_16x16x32_bf16(a10, bg[j][0], acc[2*p+1][j], 0, 0, 0);
        acc[2*p+1][j] = __builtin_amdgcn_mfma_f32_16x16x32_bf16(a11, bg[j][1], acc[2*p+1][j], 0, 0, 0);
      }
      __builtin_amdgcn_s_setprio(0);
      if (p == 1) VMCNT(4);      // A1,A3 of tile t now resident (for p2/p3 reads)
      if (p == 3) VMCNT(2);      // B*,A0,A2 of tile t+1 resident (for next p0 reads)
      __builtin_amdgcn_s_barrier();
    }
  }
  // final tile (no staging)
  {
    char* rb = smem + (((NT - 1) & 1) << 16);
#pragma unroll
    for (int p = 0; p < 4; ++p) {
      if (p == 0) {
#pragma unroll
        for (int j = 0; j < 4; ++j) {
          bg[j][0] = *(const bf16x8*)(rb + 32768 + (rowB + j * 16) * 128 + chk0);
          bg[j][1] = *(const bf16x8*)(rb + 32768 + (rowB + j * 16) * 128 + chk1);
        }
      }
      bf16x8 a00 = *(const bf16x8*)(rb + (rowA + (2 * p) * 16) * 128 + chk0);
      bf16x8 a01 = *(const bf16x8*)(rb + (rowA + (2 * p) * 16) * 128 + chk1);
      bf16x8 a10 = *(const bf16x8*)(rb + (rowA + (2 * p + 1) * 16) * 128 + chk0);
      bf16x8 a11 = *(const bf16x8*)(rb + (rowA + (2 * p + 1) * 16) * 128 + chk1);
      __builtin_amdgcn_s_barrier();
      __builtin_amdgcn_s_setprio(1);
#pragma unroll
      for (int j = 0; j < 4; ++j) {
        acc[2*p][j]   = __builtin_amdgcn_mfma_f32_16x16x32_bf16(a00, bg[j][0], acc[2*p][j], 0, 0, 0);
        acc[2*p][j]   = __builtin_amdgcn_mfma_f32_16x16x32_bf16(a01, bg[j][1], acc[2*p][j], 0, 0, 0);
        acc[2*p+1][j] = __builtin_amdgcn_mfma_f32_16x16x32_bf16(a10, bg[j][0], acc[2*p+1][j], 0, 0, 0);
        acc[2*p+1][j] = __builtin_amdgcn_mfma_f32_16x16x32_bf16(a11, bg[j][1], acc[2*p+1][j], 0, 0, 0);
      }
      __builtin_amdgcn_s_setprio(0);
      if (p == 1) VMCNT(0);      // drain A1,A3 of the last tile before p2/p3 reads
      __builtin_amdgcn_s_barrier();
    }
  }

  // epilogue: C/D layout col=lane&15, row=(lane>>4)*4+reg
  if (EPI == 2) {
    const int seg = n0 >> 10;
    const float* bp = seg == 0 ? bias0 : (seg == 1 ? bias1 : bias2);
    unsigned short* dst = seg == 0 ? Cb0 : (seg == 1 ? Cb1 : Cb2);
    float bc[4];
#pragma unroll
    for (int j = 0; j < 4; ++j) bc[j] = bp[(n0 & 1023) + wcn * 64 + j * 16 + fr];
#pragma unroll
    for (int m = 0; m < 8; ++m)
#pragma unroll
      for (int jj = 0; jj < 4; ++jj) {
        const int row = m0 + wr * 128 + m * 16 + kh * 4 + jj;
        const int b = row >> 11, s = row & (SEQ - 1);
#pragma unroll
        for (int j = 0; j < 4; ++j) {
          const int cs = (n0 & 1023) + wcn * 64 + j * 16 + fr;
          const int hh = cs >> 6, d = cs & 63;
          const float v = acc[m][j][jj] + bc[j];
          if (seg < 2)
            dst[(((size_t)(b * NH + hh)) * SEQ + s) * DEPTH + d] = f2bf(v);
          else
            dst[(((size_t)(b * NH + hh)) * DEPTH + d) * SEQ + s] = f2bf(v);
        }
      }
  } else {
    float bc[4];
#pragma unroll
    for (int j = 0; j < 4; ++j) bc[j] = bias0[n0 + wcn * 64 + j * 16 + fr];
#pragma unroll
    for (int m = 0; m < 8; ++m)
#pragma unroll
      for (int jj = 0; jj < 4; ++jj) {
        const int row = m0 + wr * 128 + m * 16 + kh * 4 + jj;
#pragma unroll
        for (int j = 0; j < 4; ++j) {
          const int col = n0 + wcn * 64 + j * 16 + fr;
          float v = acc[m][j][jj] + bc[j];
          if (EPI == 1) {
            v = fmaxf(v, 0.f);
            Cb0[(size_t)row * N + col] = f2bf(v);
          } else {
            Cf[(size_t)row * N + col] = v;
          }
        }
      }
  }
}

// ---------------- weight fp32 [K,N] -> bf16 [N,K] transpose ----------------
__global__ __launch_bounds__(256)
void transpose_to_bf16(const float* __restrict__ W, unsigned short* __restrict__ Wt,
                       int K, int N)
{
  __shared__ float t[32][33];
  const int tx = threadIdx.x & 31;
  const int ty = threadIdx.x >> 5;
  const int n0 = blockIdx.x * 32;
  const int k0 = blockIdx.y * 32;
#pragma unroll
  for (int i = 0; i < 4; ++i) {
    int r = ty + i * 8;
    t[r][tx] = W[(size_t)(k0 + r) * N + n0 + tx];
  }
  __syncthreads();
#pragma unroll
  for (int i = 0; i < 4; ++i) {
    int r = ty + i * 8;
    Wt[(size_t)(n0 + r) * K + k0 + tx] = f2bf(t[tx][r]);
  }
}

// ---------------- fp32 -> bf16 elementwise ----------------
__global__ __launch_bounds__(256)
void convert_bf16(const float* __restrict__ X, unsigned short* __restrict__ Xb, int n4)
{
  int i = blockIdx.x * 256 + threadIdx.x;
  if (i < n4) {
    float4 v = ((const float4*)X)[i];
    ushort4 r;
    r.x = f2bf(v.x); r.y = f2bf(v.y); r.z = f2bf(v.z); r.w = f2bf(v.w);
    ((ushort4*)Xb)[i] = r;
  }
}

// ---------------- bf16 MFMA flash attention (unchanged from round 4) ----------------
__global__ __launch_bounds__(256)
void attn_mfma(const unsigned short* __restrict__ Qb, const unsigned short* __restrict__ Kb,
               const unsigned short* __restrict__ Vtb, const float* __restrict__ mask,
               unsigned short* __restrict__ ctxb)
{
  __shared__ unsigned short Ks[64 * 64];
  __shared__ unsigned short Vts[64 * 64];
  __shared__ unsigned short Ps[4][16 * 72];
  __shared__ float Ms[SEQ];

  const int tid  = threadIdx.x;
  const int w    = tid >> 6;
  const int lane = tid & 63;
  const int fr   = lane & 15;
  const int kh   = lane >> 4;
  const int rbase = kh * 4;
  const int bh = blockIdx.y;
  const int b  = bh >> 4, hh = bh & 15;
  const int q0 = blockIdx.x * 64;

  for (int i = tid; i < SEQ / 4; i += 256)
    *(float4*)&Ms[i * 4] = *(const float4*)&mask[(size_t)b * SEQ + i * 4];

  const size_t qrow = ((size_t)bh * SEQ + q0 + w * 16 + fr) * DEPTH;
  bf16x8 bq[2];
  bq[0] = *(const bf16x8*)(Qb + qrow + kh * 8);
  bq[1] = *(const bf16x8*)(Qb + qrow + 32 + kh * 8);

  float m_run = -1e30f, l_run = 0.f;
  f32x4 o[4] = {};

  const int stg_chunk = (lane & 7) ^ (lane >> 3);
  const int r8 = lane >> 3;
  unsigned short* Pw = &Ps[w][0];

  for (int kv0 = 0; kv0 < SEQ; kv0 += 64) {
    __syncthreads();
#pragma unroll
    for (int i = 0; i < 2; ++i) {
      int rr = w * 16 + i * 8 + r8;
      gload_lds16((const char*)Kb + (((size_t)bh * SEQ + kv0 + rr) * DEPTH) * 2 + stg_chunk * 16,
                  (char*)Ks + (w * 16 + i * 8) * 128);
      gload_lds16((const char*)Vtb + (((size_t)bh * DEPTH + rr) * SEQ + kv0) * 2 + stg_chunk * 16,
                  (char*)Vts + (w * 16 + i * 8) * 128);
    }
    __syncthreads();

    f32x4 s[4] = {};
#pragma unroll
    for (int ks = 0; ks < 2; ++ks)
#pragma unroll
      for (int j = 0; j < 4; ++j) {
        bf16x8 ak = *(const bf16x8*)((const char*)Ks + (j * 16 + fr) * 128 +
                                     (((ks * 4 + kh) ^ (fr & 7)) * 16));
        s[j] = __builtin_amdgcn_mfma_f32_16x16x32_bf16(ak, bq[ks], s[j], 0, 0, 0);
      }

    float p[16];
    float pmax = -1e30f;
#pragma unroll
    for (int j = 0; j < 4; ++j) {
      float4 mk = *(const float4*)&Ms[kv0 + j * 16 + rbase];
#pragma unroll
      for (int jj = 0; jj < 4; ++jj) {
        float vsc = s[j][jj] * 0.125f + ((const float*)&mk)[jj] * (-1e9f);
        p[j * 4 + jj] = vsc;
        pmax = fmaxf(pmax, vsc);
      }
    }
    pmax = fmaxf(pmax, __shfl_xor(pmax, 16));
    pmax = fmaxf(pmax, __shfl_xor(pmax, 32));
    float mnew = fmaxf(m_run, pmax);
    float sc = __expf(m_run - mnew);
    float rs = 0.f;
#pragma unroll
    for (int t = 0; t < 16; ++t) { p[t] = __expf(p[t] - mnew); rs += p[t]; }
    rs += __shfl_xor(rs, 16);
    rs += __shfl_xor(rs, 32);
    l_run = l_run * sc + rs;
    m_run = mnew;
#pragma unroll
    for (int db = 0; db < 4; ++db) {
      o[db][0] *= sc; o[db][1] *= sc; o[db][2] *= sc; o[db][3] *= sc;
    }

#pragma unroll
    for (int j = 0; j < 4; ++j) {
      unsigned int lo = (unsigned)f2bf(p[j * 4 + 0]) | ((unsigned)f2bf(p[j * 4 + 1]) << 16);
      unsigned int hi = (unsigned)f2bf(p[j * 4 + 2]) | ((unsigned)f2bf(p[j * 4 + 3]) << 16);
      unsigned long long pk = (unsigned long long)lo | ((unsigned long long)hi << 32);
      *(unsigned long long*)((char*)Pw + fr * 144 + (j * 16 + rbase) * 2) = pk;
    }
#pragma unroll
    for (int ks = 0; ks < 2; ++ks) {
      bf16x8 bp = *(const bf16x8*)((char*)Pw + fr * 144 + ks * 64 + kh * 16);
#pragma unroll
      for (int db = 0; db < 4; ++db) {
        bf16x8 av = *(const bf16x8*)((const char*)Vts + (db * 16 + fr) * 128 +
                                     (((ks * 4 + kh) ^ (fr & 7)) * 16));
        o[db] = __builtin_amdgcn_mfma_f32_16x16x32_bf16(av, bp, o[db], 0, 0, 0);
      }
    }
  }

  float inv = 1.f / l_run;
  const int srow = q0 + w * 16 + fr;
#pragma unroll
  for (int db = 0; db < 4; ++db) {
    ushort4 rb;
    rb.x = f2bf(o[db][0] * inv); rb.y = f2bf(o[db][1] * inv);
    rb.z = f2bf(o[db][2] * inv); rb.w = f2bf(o[db][3] * inv);
    *(ushort4*)(ctxb + ((size_t)(b * SEQ + srow)) * DM + hh * 64 + db * 16 + rbase) = rb;
  }
}

// ---------------- out = LayerNorm(X + Y); optional bf16 copy ----------------
template<int DUAL>
__global__ __launch_bounds__(256)
void add_ln_kernel(const float* __restrict__ X, const float* __restrict__ Y,
                   const float* __restrict__ g, const float* __restrict__ be,
                   float* __restrict__ out, unsigned short* __restrict__ outb)
{
  __shared__ float red[8];
  const int row = blockIdx.x;
  const int tid = threadIdx.x;
  const size_t off = (size_t)row * DM + tid * 4;
  float4 xv = *(const float4*)(X + off);
  float4 yv = *(const float4*)(Y + off);
  float v0 = xv.x + yv.x, v1 = xv.y + yv.y, v2 = xv.z + yv.z, v3 = xv.w + yv.w;
  float s = v0 + v1 + v2 + v3;
#pragma unroll
  for (int m = 1; m < 64; m <<= 1) s += __shfl_xor(s, m);
  if ((tid & 63) == 0) red[tid >> 6] = s;
  __syncthreads();
  float mean = (red[0] + red[1] + red[2] + red[3]) * (1.f / DM);
  float d0 = v0 - mean, d1 = v1 - mean, d2 = v2 - mean, d3 = v3 - mean;
  float sq = d0 * d0 + d1 * d1 + d2 * d2 + d3 * d3;
#pragma unroll
  for (int m = 1; m < 64; m <<= 1) sq += __shfl_xor(sq, m);
  if ((tid & 63) == 0) red[4 + (tid >> 6)] = sq;
  __syncthreads();
  float var = (red[4] + red[5] + red[6] + red[7]) * (1.f / DM);
  float inv = rsqrtf(var + EPSF);
  int col = tid * 4;
  float4 r;
  r.x = d0 * inv * g[col + 0] + be[col + 0];
  r.y = d1 * inv * g[col + 1] + be[col + 1];
  r.z = d2 * inv * g[col + 2] + be[col + 2];
  r.w = d3 * inv * g[col + 3] + be[col + 3];
  *(float4*)(out + off) = r;
  if (DUAL) {
    ushort4 rb;
    rb.x = f2bf(r.x); rb.y = f2bf(r.y); rb.z = f2bf(r.z); rb.w = f2bf(r.w);
    *(ushort4*)(outb + off) = rb;
  }
}

extern "C" void kernel_launch(void* const* d_in, const int* in_sizes, int n_in,
                              void* d_out, int out_size, void* d_ws, size_t ws_size,
                              hipStream_t stream)
{
  const float* x    = (const float*)d_in[0];
  const float* mask = (const float*)d_in[1];
  const float* wq   = (const float*)d_in[2];
  const float* bq   = (const float*)d_in[3];
  const float* wk   = (const float*)d_in[4];
  const float* bk   = (const float*)d_in[5];
  const float* wv   = (const float*)d_in[6];
  const float* bv   = (const float*)d_in[7];
  const float* wo   = (const float*)d_in[8];
  const float* bo   = (const float*)d_in[9];
  const float* w1   = (const float*)d_in[10];
  const float* b1   = (const float*)d_in[11];
  const float* w2   = (const float*)d_in[12];
  const float* b2   = (const float*)d_in[13];
  const float* g1   = (const float*)d_in[14];
  const float* be1  = (const float*)d_in[15];
  const float* g2   = (const float*)d_in[16];
  const float* be2  = (const float*)d_in[17];
  float* out = (float*)d_out;
  char* wsb = (char*)d_ws;

  unsigned short* qb    = (unsigned short*)(wsb);
  unsigned short* kb    = (unsigned short*)(wsb + (16u << 20));
  unsigned short* vtb   = (unsigned short*)(wsb + (32u << 20));
  unsigned short* ctxb  = (unsigned short*)(wsb + (48u << 20));
  unsigned short* xb    = (unsigned short*)(wsb + (64u << 20));
  unsigned short* hbuf  = (unsigned short*)(wsb + (80u << 20));
  unsigned short* wqkvt = (unsigned short*)(wsb + (144u << 20));
  unsigned short* wot   = (unsigned short*)(wsb + (150u << 20));
  unsigned short* w1t   = (unsigned short*)(wsb + (152u << 20));
  unsigned short* w2t   = (unsigned short*)(wsb + (160u << 20));
  float* attn_out = (float*)(wsb);                 // [0,32)  after attention
  float* out1     = (float*)(wsb + (32u << 20));   // [32,64) after WO+LN1
  unsigned short* out1b = xb;                      // [64,80) after LN1
  float* ffn      = (float*)(wsb);                 // [0,32)  after LN1

  dim3 blk(256);
  const int M = BATCH * SEQ;   // 8192

  convert_bf16<<<8192, blk, 0, stream>>>(x, xb, (BATCH * SEQ * DM) / 4);
  transpose_to_bf16<<<dim3(32, 32), blk, 0, stream>>>(wq, wqkvt, DM, DM);
  transpose_to_bf16<<<dim3(32, 32), blk, 0, stream>>>(wk, wqkvt + 1024 * 1024, DM, DM);
  transpose_to_bf16<<<dim3(32, 32), blk, 0, stream>>>(wv, wqkvt + 2 * 1024 * 1024, DM, DM);
  transpose_to_bf16<<<dim3(32, 32), blk, 0, stream>>>(wo, wot, DM, DM);
  transpose_to_bf16<<<dim3(128, 32), blk, 0, stream>>>(w1, w1t, DM, DFF_);
  transpose_to_bf16<<<dim3(32, 128), blk, 0, stream>>>(w2, w2t, DFF_, DM);

  // fused QKV: [8192,1024] @ [3072,1024]^T -> q/k split-head + v transposed
  gemm8<2><<<dim3((M / 256) * (3072 / 256)), dim3(512), 0, stream>>>(
      xb, wqkvt, bq, bk, bv, nullptr, qb, kb, vtb, M, 3072, DM);

  attn_mfma<<<dim3(SEQ / 64, BATCH * NH), blk, 0, stream>>>(qb, kb, vtb, mask, ctxb);

  gemm8<0><<<dim3((M / 256) * (DM / 256)), dim3(512), 0, stream>>>(
      ctxb, wot, bo, nullptr, nullptr, attn_out, nullptr, nullptr, nullptr, M, DM, DM);
  add_ln_kernel<1><<<dim3(M), blk, 0, stream>>>(x, attn_out, g1, be1, out1, out1b);

  gemm8<1><<<dim3((M / 256) * (DFF_ / 256)), dim3(512), 0, stream>>>(
      out1b, w1t, b1, nullptr, nullptr, nullptr, hbuf, nullptr, nullptr, M, DFF_, DM);
  gemm8<0><<<dim3((M / 256) * (DM / 256)), dim3(512), 0, stream>>>(
      hbuf, w2t, b2, nullptr, nullptr, ffn, nullptr, nullptr, nullptr, M, DM, DFF_);

  add_ln_kernel<0><<<dim3(M), blk, 0, stream>>>(out1, ffn, g2, be2, out, nullptr);
}